// Round 6
// baseline (337.876 us; speedup 1.0000x reference)
//
#include <hip/hip_runtime.h>
#include <math.h>

// Problem constants (B,N,M,F,K) = (32,256,64,128,64)
#define PB 32
#define PN 256
#define PM 64
#define PF 128
#define PK 64
#define ROWS (PB*PN)          // 8192 atom rows
#define NTOT (ROWS*PF)        // 1048576

// bf16 weight arena offsets (elements)
#define OFF_K2F  0
#define OFF_WI   8192
#define OFF_IW1  24576
#define OFF_IW2  73728
#define OFF_WINT 122880
#define OFF_AW1  139264
#define OFF_AW2  172032
#define TOTAL_W  204800

#define XPITCH 136            // LDS row pitch (ushorts) for k_chain

typedef __attribute__((ext_vector_type(4))) float  floatx4;
typedef __attribute__((ext_vector_type(8))) short  shortx8;

__device__ __forceinline__ unsigned short f2b(float f){
    union { float f; unsigned int i; } c; c.f = f;
    unsigned int x = c.i;
    return (unsigned short)((x + 0x7fffu + ((x >> 16) & 1u)) >> 16);
}
// shifted softplus via HW transcendentals (v_exp_f32 = 2^x, v_log_f32 = log2).
// stable: max(x,0) + ln2*log2(1 + 2^(-|x|*log2e)) - ln2 ; arg of exp2 <= 0 -> no overflow.
__device__ __forceinline__ float sspf(float x){
    const float LOG2E = 1.4426950408889634f;
    const float LN2   = 0.6931471805599453f;
    float t = __builtin_amdgcn_exp2f(-fabsf(x) * LOG2E);
    return fmaxf(x, 0.0f) + LN2 * __builtin_amdgcn_logf(1.0f + t) - LN2;
}
__device__ __forceinline__ shortx8 pack8(float4 a, float4 b){
    shortx8 r;
    r[0]=(short)f2b(a.x); r[1]=(short)f2b(a.y); r[2]=(short)f2b(a.z); r[3]=(short)f2b(a.w);
    r[4]=(short)f2b(b.x); r[5]=(short)f2b(b.y); r[6]=(short)f2b(b.z); r[7]=(short)f2b(b.w);
    return r;
}

// ---- kernel 1: xa_f = ssp(x) fp32; xa_b = bf16(ssp(x)); weights -> bf16 arena ----
__global__ __launch_bounds__(256) void k_pre(const float* __restrict__ x,
                                             const float* __restrict__ k2f,
                                             const float* __restrict__ Wi,
                                             const float* __restrict__ iW1,
                                             const float* __restrict__ iW2,
                                             const float* __restrict__ Wint,
                                             const float* __restrict__ aW1,
                                             const float* __restrict__ aW2,
                                             float* __restrict__ xa_f,
                                             unsigned short* __restrict__ xa_b,
                                             unsigned short* __restrict__ Wb){
    int i = blockIdx.x * 256 + threadIdx.x;
    if (i < NTOT){
        float v = sspf(x[i]);
        xa_f[i] = v;
        xa_b[i] = f2b(v);
        return;
    }
    int j = i - NTOT;
    if (j >= TOTAL_W) return;
    float v;
    if      (j < OFF_WI)   v = k2f[j - OFF_K2F];
    else if (j < OFF_IW1)  v = Wi[j - OFF_WI];
    else if (j < OFF_IW2)  v = iW1[j - OFF_IW1];
    else if (j < OFF_WINT) v = iW2[j - OFF_IW2];
    else if (j < OFF_AW1)  v = Wint[j - OFF_WINT];
    else if (j < OFF_AW2)  v = aW1[j - OFF_AW1];
    else                   v = aW2[j - OFF_AW2];
    Wb[j] = f2b(v);
}

// ---------------- kernel 2: message aggregation, wave-per-atom, HIGH OCCUPANCY ----------------
// Round-6 structural change: every prior variant was pinned to 1 block/CU by a
// 132 KB LDS xa image -> 8 waves/CU -> latency exposure (per-wave wall ~4.7 us/iter
// vs ~0.3 us of pipe work). xa_f is only 4 MB total and freshly written by k_pre, so
// it is L2/L3-resident: gather it FROM GLOBAL (~268 MB of L2-class reads ~ 8 us
// aggregate) and keep only the 16 KB fragment-ordered k2f copy in LDS.
//   - block = 256 thr (4 waves); wave w owns atom blockIdx*4+w entirely (4 m-tiles).
//   - rbf: 2-deep register ping-pong (sets A/B), the only HBM stream.
//   - one barrier total (weight staging); no cross-wave coupling after it.
//   - live set ~95 VGPR; __launch_bounds__(256,4) caps at 128 -> 4 blocks/CU,
//     16 waves/CU: 8x the wave concurrency of rounds 2-5.
__global__ __launch_bounds__(256, 4) void k_msg(const float* __restrict__ rbf,
                                                const int* __restrict__ nbr,
                                                const unsigned short* __restrict__ Wk2f, // bf16
                                                const float* __restrict__ xa_f,
                                                float* __restrict__ xj){
    const int tid  = threadIdx.x;
    const int w    = tid >> 6;        // wave 0..3
    const int lane = tid & 63;
    const int quad = lane >> 4;
    const int l16  = lane & 15;

    const int atom = blockIdx.x * 4 + w;          // 0..8191
    const int b    = atom >> 8;                   // batch image

    __shared__ unsigned short w_s[8192];          // 16 KB k2f frags, fragment-ordered

    const int rboff = l16 * PK + quad*8;          // lane offset inside one m-tile
    const float* rb_base = rbf + (size_t)atom * (PM*PK);
    const int*   nb_base = nbr + (size_t)atom * PM + quad*4;
    const float* xab     = xa_f + (size_t)b * (PN*PF) + l16;

    // ---- issue t=0 and t=1 rbf/nbr loads (2-deep ping-pong) ----
    float4 a0,a1,a2,a3, b0v,b1v,b2v,b3v;
    int4 nbA, nbB;
    {
        const float* p0 = rb_base + rboff;               // t=0
        a0 = *(const float4*)(p0);
        a1 = *(const float4*)(p0 + 4);
        a2 = *(const float4*)(p0 + 32);
        a3 = *(const float4*)(p0 + 36);
        nbA = *(const int4*)(nb_base);
        const float* p1 = rb_base + 16*PK + rboff;       // t=1
        b0v = *(const float4*)(p1);
        b1v = *(const float4*)(p1 + 4);
        b2v = *(const float4*)(p1 + 32);
        b3v = *(const float4*)(p1 + 36);
        nbB = *(const int4*)(nb_base + 16);
    }

    // ---- stage k2f weights into LDS in fragment order (1024 frags x 16 B) ----
    // frag f = (s, ft, ln): holds Wk2f[(ft*16 + (ln&15))*64 + s*32 + (ln>>4)*8 + j]
    #pragma unroll
    for (int rep = 0; rep < 4; ++rep){
        int f  = rep*256 + tid;
        int s  = f >> 9;
        int ft = (f >> 6) & 7;
        int ln = f & 63;
        const unsigned short* g = Wk2f + (size_t)(ft*16 + (ln & 15))*PK + s*32 + (ln >> 4)*8;
        *(shortx8*)(&w_s[f*8]) = *(const shortx8*)(g);
    }
    __syncthreads();   // the only barrier

    float s[8];
    #pragma unroll
    for (int t = 0; t < 4; ++t){
        // consume the prefetched f32 tile -> bf16 A-frags
        shortx8 af0, af1; int4 nbc;
        if ((t & 1) == 0){ af0 = pack8(a0, a1);  af1 = pack8(a2, a3);  nbc = nbA; }
        else             { af0 = pack8(b0v, b1v); af1 = pack8(b2v, b3v); nbc = nbB; }

        // refill the just-consumed set for tile t+2
        if (t + 2 < 4){
            const float* pn = rb_base + (t+2)*16*PK + rboff;
            const int4*  nn = (const int4*)(nb_base + (t+2)*16);
            if ((t & 1) == 0){
                a0 = *(const float4*)(pn);
                a1 = *(const float4*)(pn + 4);
                a2 = *(const float4*)(pn + 32);
                a3 = *(const float4*)(pn + 36);
                nbA = *nn;
            } else {
                b0v = *(const float4*)(pn);
                b1v = *(const float4*)(pn + 4);
                b2v = *(const float4*)(pn + 32);
                b3v = *(const float4*)(pn + 36);
                nbB = *nn;
            }
        }

        // gather row bases for this tile's 4 m-rows (per quad), global (L2-resident)
        const float* rp0 = xab + (size_t)nbc.x * PF;
        const float* rp1 = xab + (size_t)nbc.y * PF;
        const float* rp2 = xab + (size_t)nbc.z * PF;
        const float* rp3 = xab + (size_t)nbc.w * PF;

        // interleaved ft loop: 2 ds_read_b128 -> 2 MFMA -> 4 global gathers -> 4 fma
        #pragma unroll
        for (int ft = 0; ft < 8; ++ft){
            shortx8 w0 = *(const shortx8*)(&w_s[(ft*64 + lane)*8]);        // s=0
            shortx8 w1 = *(const shortx8*)(&w_s[((8 + ft)*64 + lane)*8]);  // s=1
            floatx4 c = {0.f, 0.f, 0.f, 0.f};
            c = __builtin_amdgcn_mfma_f32_16x16x32_bf16(af0, w0, c, 0, 0, 0);
            c = __builtin_amdgcn_mfma_f32_16x16x32_bf16(af1, w1, c, 0, 0, 0);
            float v =  c[0] * rp0[ft*16];
            v       += c[1] * rp1[ft*16];
            v       += c[2] * rp2[ft*16];
            v       += c[3] * rp3[ft*16];
            if (t == 0) s[ft] = v; else s[ft] += v;
        }
    }

    // quad-reduce (m) and store this wave's atom
    #pragma unroll
    for (int ft = 0; ft < 8; ++ft){
        float v = s[ft];
        v += __shfl_xor(v, 16, 64);
        v += __shfl_xor(v, 32, 64);
        if (quad == 0) xj[(size_t)atom*PF + ft*16 + l16] = v;
    }
}

// ---------------- kernel 3: fused 12-stage chain, weight-pipelined ----------------
__device__ __forceinline__ void lw8(const unsigned short* __restrict__ W,
                                    int l16, int quad, int ftb, shortx8 wf[8]){
    #pragma unroll
    for (int f = 0; f < 2; ++f)
        #pragma unroll
        for (int ks = 0; ks < 4; ++ks)
            wf[f*4+ks] = *(const shortx8*)(W + (size_t)((ftb+f)*16 + l16)*PF + ks*32 + quad*8);
}
__device__ __forceinline__ void gemm2p(const shortx8 wf[8], const shortx8 a[4], floatx4 acc[2]){
    #pragma unroll
    for (int f = 0; f < 2; ++f){
        floatx4 c = {0.f, 0.f, 0.f, 0.f};
        #pragma unroll
        for (int ks = 0; ks < 4; ++ks)
            c = __builtin_amdgcn_mfma_f32_16x16x32_bf16(a[ks], wf[f*4+ks], c, 0, 0, 0);
        acc[f] = c;
    }
}

// write C-layout t16 into buffer p, barrier once, read back A-frags
__device__ __forceinline__ void relayout(unsigned short* Tls,   // base of buffer p
                                         const unsigned short t16[8],
                                         int l16, int quad, int ftbase,
                                         shortx8 a[4]){
    #pragma unroll
    for (int f = 0; f < 2; ++f)
        #pragma unroll
        for (int r = 0; r < 4; ++r)
            Tls[(quad*4 + r)*XPITCH + (ftbase+f)*16 + l16] = t16[f*4 + r];
    __syncthreads();   // RAW; WAR across stages handled by double-buffering
    #pragma unroll
    for (int ks = 0; ks < 4; ++ks)
        a[ks] = *(const shortx8*)(Tls + l16*XPITCH + ks*32 + quad*8);
}

__global__ __launch_bounds__(256) void k_chain(const unsigned short* __restrict__ xa_b,
                                               const float* __restrict__ xj,
                                               const float* __restrict__ x,
                                               const unsigned short* __restrict__ Wb,
                                               const float* __restrict__ bi,
                                               const float* __restrict__ ib1,
                                               const float* __restrict__ ib2,
                                               const float* __restrict__ bint,
                                               const float* __restrict__ ugate,
                                               const float* __restrict__ ab1,
                                               const float* __restrict__ ab2,
                                               float* __restrict__ out){
    const int tid  = threadIdx.x;
    const int wave = tid >> 6;
    const int lane = tid & 63;
    const int quad = lane >> 4;
    const int l16  = lane & 15;
    const int ftb  = wave*2;
    const int row0 = blockIdx.x * 16;

    __shared__ unsigned short Tls[2][16 * XPITCH];   // 8.5 KB double buffer
    int p = 0;

    int col[2];
    #pragma unroll
    for (int f = 0; f < 2; ++f) col[f] = (ftb+f)*16 + l16;

    const unsigned short* inrow = xa_b + (size_t)(row0 + l16) * PF;
    shortx8 a[4];
    #pragma unroll
    for (int ks = 0; ks < 4; ++ks)
        a[ks] = *(const shortx8*)(inrow + ks*32 + quad*8);

    shortx8 wA[8], wB[8];
    lw8(Wb + OFF_WI, l16, quad, ftb, wA);            // stage-0 weights

    floatx4 acc[2];
    float V[8];
    unsigned short t16[8];

    // ---- stage A: v = ssp(xa@Wi^T + bi) + xj ----
    lw8(Wb + OFF_IW1, l16, quad, ftb, wB);           // prefetch IW1[0]
    gemm2p(wA, a, acc);
    #pragma unroll
    for (int f = 0; f < 2; ++f)
        #pragma unroll
        for (int r = 0; r < 4; ++r){
            size_t idx = (size_t)(row0 + quad*4 + r)*PF + col[f];
            float of = sspf(acc[f][r] + bi[col[f]]) + xj[idx];
            V[f*4+r] = of;
            t16[f*4+r] = f2b(sspf(of));
        }
    relayout(Tls[p], t16, l16, quad, ftb, a); p ^= 1;

    // ---- 3 interaction residual blocks ----
    #pragma unroll
    for (int l = 0; l < 3; ++l){
        lw8(Wb + OFF_IW2 + l*PF*PF, l16, quad, ftb, wA);   // prefetch IW2[l]
        gemm2p(wB, a, acc);                                 // use IW1[l]
        #pragma unroll
        for (int f = 0; f < 2; ++f)
            #pragma unroll
            for (int r = 0; r < 4; ++r)
                t16[f*4+r] = f2b(sspf(acc[f][r] + ib1[l*PF + col[f]]));
        relayout(Tls[p], t16, l16, quad, ftb, a); p ^= 1;

        lw8(Wb + (l < 2 ? OFF_IW1 + (l+1)*PF*PF : OFF_WINT), l16, quad, ftb, wB);
        gemm2p(wA, a, acc);                                 // use IW2[l]
        #pragma unroll
        for (int f = 0; f < 2; ++f)
            #pragma unroll
            for (int r = 0; r < 4; ++r){
                V[f*4+r] += acc[f][r] + ib2[l*PF + col[f]];
                t16[f*4+r] = f2b(sspf(V[f*4+r]));
            }
        relayout(Tls[p], t16, l16, quad, ftb, a); p ^= 1;
    }

    // ---- gate: out = u_gate*x + ssp(v)@Wint^T + bint ----
    lw8(Wb + OFF_AW1, l16, quad, ftb, wA);                  // prefetch AW1[0]
    gemm2p(wB, a, acc);                                     // use WINT
    #pragma unroll
    for (int f = 0; f < 2; ++f)
        #pragma unroll
        for (int r = 0; r < 4; ++r){
            size_t idx = (size_t)(row0 + quad*4 + r)*PF + col[f];
            float o = ugate[col[f]] * x[idx] + acc[f][r] + bint[col[f]];
            V[f*4+r] = o;
            t16[f*4+r] = f2b(sspf(o));
        }
    relayout(Tls[p], t16, l16, quad, ftb, a); p ^= 1;

    // ---- 2 atom residual blocks ----
    #pragma unroll
    for (int l = 0; l < 2; ++l){
        lw8(Wb + OFF_AW2 + l*PF*PF, l16, quad, ftb, wB);    // prefetch AW2[l]
        gemm2p(wA, a, acc);                                 // use AW1[l]
        #pragma unroll
        for (int f = 0; f < 2; ++f)
            #pragma unroll
            for (int r = 0; r < 4; ++r)
                t16[f*4+r] = f2b(sspf(acc[f][r] + ab1[l*PF + col[f]]));
        relayout(Tls[p], t16, l16, quad, ftb, a); p ^= 1;

        if (l == 0) lw8(Wb + OFF_AW1 + PF*PF, l16, quad, ftb, wA);  // prefetch AW1[1]
        gemm2p(wB, a, acc);                                 // use AW2[l]
        if (l == 0){
            #pragma unroll
            for (int f = 0; f < 2; ++f)
                #pragma unroll
                for (int r = 0; r < 4; ++r){
                    V[f*4+r] += acc[f][r] + ab2[l*PF + col[f]];
                    t16[f*4+r] = f2b(sspf(V[f*4+r]));
                }
            relayout(Tls[p], t16, l16, quad, ftb, a); p ^= 1;
        } else {
            #pragma unroll
            for (int f = 0; f < 2; ++f)
                #pragma unroll
                for (int r = 0; r < 4; ++r){
                    size_t idx = (size_t)(row0 + quad*4 + r)*PF + col[f];
                    out[idx] = V[f*4+r] + acc[f][r] + ab2[l*PF + col[f]];
                }
        }
    }
}

extern "C" void kernel_launch(void* const* d_in, const int* in_sizes, int n_in,
                              void* d_out, int out_size, void* d_ws, size_t ws_size,
                              hipStream_t stream){
    const float* x     = (const float*)d_in[0];
    const float* rbf   = (const float*)d_in[1];
    const int*   nbr   = (const int*)d_in[2];
    const float* k2fW  = (const float*)d_in[3];
    const float* Wi    = (const float*)d_in[4];
    const float* bi    = (const float*)d_in[5];
    const float* iW1   = (const float*)d_in[6];
    const float* ib1   = (const float*)d_in[7];
    const float* iW2   = (const float*)d_in[8];
    const float* ib2   = (const float*)d_in[9];
    const float* Wint  = (const float*)d_in[10];
    const float* bint  = (const float*)d_in[11];
    const float* ugate = (const float*)d_in[12];
    const float* aW1   = (const float*)d_in[13];
    const float* ab1   = (const float*)d_in[14];
    const float* aW2   = (const float*)d_in[15];
    const float* ab2   = (const float*)d_in[16];

    // Workspace (~10.4 MB):
    //   xa_b [0,2MB) bf16 ; xa_f [2,6MB) fp32 ; xj [6,10MB) fp32 ; Wb [10MB,+400K)
    char* ws = (char*)d_ws;
    unsigned short* xa_b = (unsigned short*)ws;
    float*          xa_f = (float*)(ws + (2ull  << 20));
    float*          xj   = (float*)(ws + (6ull  << 20));
    unsigned short* Wb   = (unsigned short*)(ws + (10ull << 20));

    k_pre<<<(NTOT + TOTAL_W + 255)/256, 256, 0, stream>>>(
        x, k2fW, Wi, iW1, iW2, Wint, aW1, aW2, xa_f, xa_b, Wb);
    k_msg<<<ROWS/4, 256, 0, stream>>>(rbf, nbr, Wb + OFF_K2F, xa_f, xj);
    k_chain<<<ROWS/16, 256, 0, stream>>>(xa_b, xj, x, Wb,
                                         bi, ib1, ib2, bint, ugate, ab1, ab2,
                                         (float*)d_out);
}

// Round 7
// 266.873 us; speedup vs baseline: 1.2661x; 1.2661x over previous
//
#include <hip/hip_runtime.h>
#include <math.h>

// Problem constants (B,N,M,F,K) = (32,256,64,128,64)
#define PB 32
#define PN 256
#define PM 64
#define PF 128
#define PK 64
#define ROWS (PB*PN)          // 8192 atom rows
#define NTOT (ROWS*PF)        // 1048576

// bf16 weight arena offsets (elements)
#define OFF_K2F  0
#define OFF_WI   8192
#define OFF_IW1  24576
#define OFF_IW2  73728
#define OFF_WINT 122880
#define OFF_AW1  139264
#define OFF_AW2  172032
#define TOTAL_W  204800

#define XPITCH 136            // LDS row pitch (ushorts) for k_chain

typedef __attribute__((ext_vector_type(4))) float  floatx4;
typedef __attribute__((ext_vector_type(8))) short  shortx8;

__device__ __forceinline__ unsigned short f2b(float f){
    union { float f; unsigned int i; } c; c.f = f;
    unsigned int x = c.i;
    return (unsigned short)((x + 0x7fffu + ((x >> 16) & 1u)) >> 16);
}
// shifted softplus via HW transcendentals (v_exp_f32 = 2^x, v_log_f32 = log2).
// stable: max(x,0) + ln2*log2(1 + 2^(-|x|*log2e)) - ln2 ; arg of exp2 <= 0 -> no overflow.
__device__ __forceinline__ float sspf(float x){
    const float LOG2E = 1.4426950408889634f;
    const float LN2   = 0.6931471805599453f;
    float t = __builtin_amdgcn_exp2f(-fabsf(x) * LOG2E);
    return fmaxf(x, 0.0f) + LN2 * __builtin_amdgcn_logf(1.0f + t) - LN2;
}
__device__ __forceinline__ shortx8 pack8(float4 a, float4 b){
    shortx8 r;
    r[0]=(short)f2b(a.x); r[1]=(short)f2b(a.y); r[2]=(short)f2b(a.z); r[3]=(short)f2b(a.w);
    r[4]=(short)f2b(b.x); r[5]=(short)f2b(b.y); r[6]=(short)f2b(b.z); r[7]=(short)f2b(b.w);
    return r;
}

// ---- kernel 1: xa_f = ssp(x) fp32; xa_b = bf16(ssp(x)); weights -> bf16 arena ----
__global__ __launch_bounds__(256) void k_pre(const float* __restrict__ x,
                                             const float* __restrict__ k2f,
                                             const float* __restrict__ Wi,
                                             const float* __restrict__ iW1,
                                             const float* __restrict__ iW2,
                                             const float* __restrict__ Wint,
                                             const float* __restrict__ aW1,
                                             const float* __restrict__ aW2,
                                             float* __restrict__ xa_f,
                                             unsigned short* __restrict__ xa_b,
                                             unsigned short* __restrict__ Wb){
    int i = blockIdx.x * 256 + threadIdx.x;
    if (i < NTOT){
        float v = sspf(x[i]);
        xa_f[i] = v;
        xa_b[i] = f2b(v);
        return;
    }
    int j = i - NTOT;
    if (j >= TOTAL_W) return;
    float v;
    if      (j < OFF_WI)   v = k2f[j - OFF_K2F];
    else if (j < OFF_IW1)  v = Wi[j - OFF_WI];
    else if (j < OFF_IW2)  v = iW1[j - OFF_IW1];
    else if (j < OFF_WINT) v = iW2[j - OFF_IW2];
    else if (j < OFF_AW1)  v = Wint[j - OFF_WINT];
    else if (j < OFF_AW2)  v = aW1[j - OFF_AW1];
    else                   v = aW2[j - OFF_AW2];
    Wb[j] = f2b(v);
}

// ---------------- kernel 2: message aggregation, wave-per-atom, HIGH OCCUPANCY ----------------
// Structure as round 6 (16 KB fragment-ordered k2f LDS; global gather from L2-resident
// xa_f; one barrier; wave-per-atom with 2-deep rbf ping-pong).
// ROUND-7 FIX: plain __launch_bounds__(256) with NO min-waves arg. Every constrained
// variant (512,2 / 512 / 256,4) made the allocator pick an occupancy-greedy VGPR tier
// BELOW the live set (128, 128, 64) and spill 35-50 regs -> 150-230 MB scratch HBM
// traffic. Every unconstrained kernel in this session allocated to fit (R0: 148 VGPR,
// WRITE=4MB, zero spill). Live set here ~100 VGPR -> expect ~100-160 VGPR, no scratch,
// ~4 waves/EU from the register tier alone.
__global__ __launch_bounds__(256) void k_msg(const float* __restrict__ rbf,
                                             const int* __restrict__ nbr,
                                             const unsigned short* __restrict__ Wk2f, // bf16
                                             const float* __restrict__ xa_f,
                                             float* __restrict__ xj){
    const int tid  = threadIdx.x;
    const int w    = tid >> 6;        // wave 0..3
    const int lane = tid & 63;
    const int quad = lane >> 4;
    const int l16  = lane & 15;

    const int atom = blockIdx.x * 4 + w;          // 0..8191
    const int b    = atom >> 8;                   // batch image

    __shared__ unsigned short w_s[8192];          // 16 KB k2f frags, fragment-ordered

    const int rboff = l16 * PK + quad*8;          // lane offset inside one m-tile
    const float* rb_base = rbf + (size_t)atom * (PM*PK);
    const int*   nb_base = nbr + (size_t)atom * PM + quad*4;
    const float* xab     = xa_f + (size_t)b * (PN*PF) + l16;

    // ---- issue t=0 and t=1 rbf/nbr loads (2-deep ping-pong) ----
    float4 a0,a1,a2,a3, b0v,b1v,b2v,b3v;
    int4 nbA, nbB;
    {
        const float* p0 = rb_base + rboff;               // t=0
        a0 = *(const float4*)(p0);
        a1 = *(const float4*)(p0 + 4);
        a2 = *(const float4*)(p0 + 32);
        a3 = *(const float4*)(p0 + 36);
        nbA = *(const int4*)(nb_base);
        const float* p1 = rb_base + 16*PK + rboff;       // t=1
        b0v = *(const float4*)(p1);
        b1v = *(const float4*)(p1 + 4);
        b2v = *(const float4*)(p1 + 32);
        b3v = *(const float4*)(p1 + 36);
        nbB = *(const int4*)(nb_base + 16);
    }

    // ---- stage k2f weights into LDS in fragment order (1024 frags x 16 B) ----
    // frag f = (s, ft, ln): holds Wk2f[(ft*16 + (ln&15))*64 + s*32 + (ln>>4)*8 + j]
    #pragma unroll
    for (int rep = 0; rep < 4; ++rep){
        int f  = rep*256 + tid;
        int s  = f >> 9;
        int ft = (f >> 6) & 7;
        int ln = f & 63;
        const unsigned short* g = Wk2f + (size_t)(ft*16 + (ln & 15))*PK + s*32 + (ln >> 4)*8;
        *(shortx8*)(&w_s[f*8]) = *(const shortx8*)(g);
    }
    __syncthreads();   // the only barrier

    float s[8];
    #pragma unroll
    for (int t = 0; t < 4; ++t){
        // consume the prefetched f32 tile -> bf16 A-frags
        shortx8 af0, af1; int4 nbc;
        if ((t & 1) == 0){ af0 = pack8(a0, a1);  af1 = pack8(a2, a3);  nbc = nbA; }
        else             { af0 = pack8(b0v, b1v); af1 = pack8(b2v, b3v); nbc = nbB; }

        // refill the just-consumed set for tile t+2
        if (t + 2 < 4){
            const float* pn = rb_base + (t+2)*16*PK + rboff;
            const int4*  nn = (const int4*)(nb_base + (t+2)*16);
            if ((t & 1) == 0){
                a0 = *(const float4*)(pn);
                a1 = *(const float4*)(pn + 4);
                a2 = *(const float4*)(pn + 32);
                a3 = *(const float4*)(pn + 36);
                nbA = *nn;
            } else {
                b0v = *(const float4*)(pn);
                b1v = *(const float4*)(pn + 4);
                b2v = *(const float4*)(pn + 32);
                b3v = *(const float4*)(pn + 36);
                nbB = *nn;
            }
        }

        // gather row bases for this tile's 4 m-rows (per quad), global (L2-resident)
        const float* rp0 = xab + (size_t)nbc.x * PF;
        const float* rp1 = xab + (size_t)nbc.y * PF;
        const float* rp2 = xab + (size_t)nbc.z * PF;
        const float* rp3 = xab + (size_t)nbc.w * PF;

        // interleaved ft loop: 2 ds_read_b128 -> 2 MFMA -> 4 global gathers -> 4 fma
        #pragma unroll
        for (int ft = 0; ft < 8; ++ft){
            shortx8 w0 = *(const shortx8*)(&w_s[(ft*64 + lane)*8]);        // s=0
            shortx8 w1 = *(const shortx8*)(&w_s[((8 + ft)*64 + lane)*8]);  // s=1
            floatx4 c = {0.f, 0.f, 0.f, 0.f};
            c = __builtin_amdgcn_mfma_f32_16x16x32_bf16(af0, w0, c, 0, 0, 0);
            c = __builtin_amdgcn_mfma_f32_16x16x32_bf16(af1, w1, c, 0, 0, 0);
            float v =  c[0] * rp0[ft*16];
            v       += c[1] * rp1[ft*16];
            v       += c[2] * rp2[ft*16];
            v       += c[3] * rp3[ft*16];
            if (t == 0) s[ft] = v; else s[ft] += v;
        }
    }

    // quad-reduce (m) and store this wave's atom
    #pragma unroll
    for (int ft = 0; ft < 8; ++ft){
        float v = s[ft];
        v += __shfl_xor(v, 16, 64);
        v += __shfl_xor(v, 32, 64);
        if (quad == 0) xj[(size_t)atom*PF + ft*16 + l16] = v;
    }
}

// ---------------- kernel 3: fused 12-stage chain, weight-pipelined ----------------
__device__ __forceinline__ void lw8(const unsigned short* __restrict__ W,
                                    int l16, int quad, int ftb, shortx8 wf[8]){
    #pragma unroll
    for (int f = 0; f < 2; ++f)
        #pragma unroll
        for (int ks = 0; ks < 4; ++ks)
            wf[f*4+ks] = *(const shortx8*)(W + (size_t)((ftb+f)*16 + l16)*PF + ks*32 + quad*8);
}
__device__ __forceinline__ void gemm2p(const shortx8 wf[8], const shortx8 a[4], floatx4 acc[2]){
    #pragma unroll
    for (int f = 0; f < 2; ++f){
        floatx4 c = {0.f, 0.f, 0.f, 0.f};
        #pragma unroll
        for (int ks = 0; ks < 4; ++ks)
            c = __builtin_amdgcn_mfma_f32_16x16x32_bf16(a[ks], wf[f*4+ks], c, 0, 0, 0);
        acc[f] = c;
    }
}

// write C-layout t16 into buffer p, barrier once, read back A-frags
__device__ __forceinline__ void relayout(unsigned short* Tls,   // base of buffer p
                                         const unsigned short t16[8],
                                         int l16, int quad, int ftbase,
                                         shortx8 a[4]){
    #pragma unroll
    for (int f = 0; f < 2; ++f)
        #pragma unroll
        for (int r = 0; r < 4; ++r)
            Tls[(quad*4 + r)*XPITCH + (ftbase+f)*16 + l16] = t16[f*4 + r];
    __syncthreads();   // RAW; WAR across stages handled by double-buffering
    #pragma unroll
    for (int ks = 0; ks < 4; ++ks)
        a[ks] = *(const shortx8*)(Tls + l16*XPITCH + ks*32 + quad*8);
}

__global__ __launch_bounds__(256) void k_chain(const unsigned short* __restrict__ xa_b,
                                               const float* __restrict__ xj,
                                               const float* __restrict__ x,
                                               const unsigned short* __restrict__ Wb,
                                               const float* __restrict__ bi,
                                               const float* __restrict__ ib1,
                                               const float* __restrict__ ib2,
                                               const float* __restrict__ bint,
                                               const float* __restrict__ ugate,
                                               const float* __restrict__ ab1,
                                               const float* __restrict__ ab2,
                                               float* __restrict__ out){
    const int tid  = threadIdx.x;
    const int wave = tid >> 6;
    const int lane = tid & 63;
    const int quad = lane >> 4;
    const int l16  = lane & 15;
    const int ftb  = wave*2;
    const int row0 = blockIdx.x * 16;

    __shared__ unsigned short Tls[2][16 * XPITCH];   // 8.5 KB double buffer
    int p = 0;

    int col[2];
    #pragma unroll
    for (int f = 0; f < 2; ++f) col[f] = (ftb+f)*16 + l16;

    const unsigned short* inrow = xa_b + (size_t)(row0 + l16) * PF;
    shortx8 a[4];
    #pragma unroll
    for (int ks = 0; ks < 4; ++ks)
        a[ks] = *(const shortx8*)(inrow + ks*32 + quad*8);

    shortx8 wA[8], wB[8];
    lw8(Wb + OFF_WI, l16, quad, ftb, wA);            // stage-0 weights

    floatx4 acc[2];
    float V[8];
    unsigned short t16[8];

    // ---- stage A: v = ssp(xa@Wi^T + bi) + xj ----
    lw8(Wb + OFF_IW1, l16, quad, ftb, wB);           // prefetch IW1[0]
    gemm2p(wA, a, acc);
    #pragma unroll
    for (int f = 0; f < 2; ++f)
        #pragma unroll
        for (int r = 0; r < 4; ++r){
            size_t idx = (size_t)(row0 + quad*4 + r)*PF + col[f];
            float of = sspf(acc[f][r] + bi[col[f]]) + xj[idx];
            V[f*4+r] = of;
            t16[f*4+r] = f2b(sspf(of));
        }
    relayout(Tls[p], t16, l16, quad, ftb, a); p ^= 1;

    // ---- 3 interaction residual blocks ----
    #pragma unroll
    for (int l = 0; l < 3; ++l){
        lw8(Wb + OFF_IW2 + l*PF*PF, l16, quad, ftb, wA);   // prefetch IW2[l]
        gemm2p(wB, a, acc);                                 // use IW1[l]
        #pragma unroll
        for (int f = 0; f < 2; ++f)
            #pragma unroll
            for (int r = 0; r < 4; ++r)
                t16[f*4+r] = f2b(sspf(acc[f][r] + ib1[l*PF + col[f]]));
        relayout(Tls[p], t16, l16, quad, ftb, a); p ^= 1;

        lw8(Wb + (l < 2 ? OFF_IW1 + (l+1)*PF*PF : OFF_WINT), l16, quad, ftb, wB);
        gemm2p(wA, a, acc);                                 // use IW2[l]
        #pragma unroll
        for (int f = 0; f < 2; ++f)
            #pragma unroll
            for (int r = 0; r < 4; ++r){
                V[f*4+r] += acc[f][r] + ib2[l*PF + col[f]];
                t16[f*4+r] = f2b(sspf(V[f*4+r]));
            }
        relayout(Tls[p], t16, l16, quad, ftb, a); p ^= 1;
    }

    // ---- gate: out = u_gate*x + ssp(v)@Wint^T + bint ----
    lw8(Wb + OFF_AW1, l16, quad, ftb, wA);                  // prefetch AW1[0]
    gemm2p(wB, a, acc);                                     // use WINT
    #pragma unroll
    for (int f = 0; f < 2; ++f)
        #pragma unroll
        for (int r = 0; r < 4; ++r){
            size_t idx = (size_t)(row0 + quad*4 + r)*PF + col[f];
            float o = ugate[col[f]] * x[idx] + acc[f][r] + bint[col[f]];
            V[f*4+r] = o;
            t16[f*4+r] = f2b(sspf(o));
        }
    relayout(Tls[p], t16, l16, quad, ftb, a); p ^= 1;

    // ---- 2 atom residual blocks ----
    #pragma unroll
    for (int l = 0; l < 2; ++l){
        lw8(Wb + OFF_AW2 + l*PF*PF, l16, quad, ftb, wB);    // prefetch AW2[l]
        gemm2p(wA, a, acc);                                 // use AW1[l]
        #pragma unroll
        for (int f = 0; f < 2; ++f)
            #pragma unroll
            for (int r = 0; r < 4; ++r)
                t16[f*4+r] = f2b(sspf(acc[f][r] + ab1[l*PF + col[f]]));
        relayout(Tls[p], t16, l16, quad, ftb, a); p ^= 1;

        if (l == 0) lw8(Wb + OFF_AW1 + PF*PF, l16, quad, ftb, wA);  // prefetch AW1[1]
        gemm2p(wB, a, acc);                                 // use AW2[l]
        if (l == 0){
            #pragma unroll
            for (int f = 0; f < 2; ++f)
                #pragma unroll
                for (int r = 0; r < 4; ++r){
                    V[f*4+r] += acc[f][r] + ab2[l*PF + col[f]];
                    t16[f*4+r] = f2b(sspf(V[f*4+r]));
                }
            relayout(Tls[p], t16, l16, quad, ftb, a); p ^= 1;
        } else {
            #pragma unroll
            for (int f = 0; f < 2; ++f)
                #pragma unroll
                for (int r = 0; r < 4; ++r){
                    size_t idx = (size_t)(row0 + quad*4 + r)*PF + col[f];
                    out[idx] = V[f*4+r] + acc[f][r] + ab2[l*PF + col[f]];
                }
        }
    }
}

extern "C" void kernel_launch(void* const* d_in, const int* in_sizes, int n_in,
                              void* d_out, int out_size, void* d_ws, size_t ws_size,
                              hipStream_t stream){
    const float* x     = (const float*)d_in[0];
    const float* rbf   = (const float*)d_in[1];
    const int*   nbr   = (const int*)d_in[2];
    const float* k2fW  = (const float*)d_in[3];
    const float* Wi    = (const float*)d_in[4];
    const float* bi    = (const float*)d_in[5];
    const float* iW1   = (const float*)d_in[6];
    const float* ib1   = (const float*)d_in[7];
    const float* iW2   = (const float*)d_in[8];
    const float* ib2   = (const float*)d_in[9];
    const float* Wint  = (const float*)d_in[10];
    const float* bint  = (const float*)d_in[11];
    const float* ugate = (const float*)d_in[12];
    const float* aW1   = (const float*)d_in[13];
    const float* ab1   = (const float*)d_in[14];
    const float* aW2   = (const float*)d_in[15];
    const float* ab2   = (const float*)d_in[16];

    // Workspace (~10.4 MB):
    //   xa_b [0,2MB) bf16 ; xa_f [2,6MB) fp32 ; xj [6,10MB) fp32 ; Wb [10MB,+400K)
    char* ws = (char*)d_ws;
    unsigned short* xa_b = (unsigned short*)ws;
    float*          xa_f = (float*)(ws + (2ull  << 20));
    float*          xj   = (float*)(ws + (6ull  << 20));
    unsigned short* Wb   = (unsigned short*)(ws + (10ull << 20));

    k_pre<<<(NTOT + TOTAL_W + 255)/256, 256, 0, stream>>>(
        x, k2fW, Wi, iW1, iW2, Wint, aW1, aW2, xa_f, xa_b, Wb);
    k_msg<<<ROWS/4, 256, 0, stream>>>(rbf, nbr, Wb + OFF_K2F, xa_f, xj);
    k_chain<<<ROWS/16, 256, 0, stream>>>(xa_b, xj, x, Wb,
                                         bi, ib1, ib2, bint, ugate, ab1, ab2,
                                         (float*)d_out);
}